// Round 4
// baseline (1526.823 us; speedup 1.0000x reference)
//
#include <hip/hip_runtime.h>

typedef unsigned short u16;
typedef __attribute__((ext_vector_type(8))) short short8;
typedef __attribute__((ext_vector_type(4))) float f32x4;

__device__ __forceinline__ u16 f2bf(float f) {
  union { float f; unsigned u; } v; v.f = f;
  unsigned r = v.u + 0x7fffu + ((v.u >> 16) & 1u);
  return (u16)(r >> 16);
}
__device__ __forceinline__ u16 truncbf(float f) {
  union { float f; unsigned u; } v; v.f = f;
  return (u16)(v.u >> 16);
}
__device__ __forceinline__ float bf2f(u16 h) {
  union { unsigned u; float f; } v; v.u = ((unsigned)h) << 16;
  return v.f;
}
// async global->LDS, 16B per lane; LDS dest = wave-uniform base (HW adds lane*16), 16B aligned
__device__ __forceinline__ void gll16(const void* g, void* l) {
  __builtin_amdgcn_global_load_lds((const __attribute__((address_space(1))) unsigned*)g,
                                   (__attribute__((address_space(3))) unsigned*)l, 16, 0, 0);
}
// Workgroup barrier that orders LDS only (no vmcnt drain). Used in k_front only (proven win);
// k_gru keeps __syncthreads (R8/R9 post-mortem: drain there is cheap, asm fences neutral-to-bad).
__device__ __forceinline__ void bar_lds() {
  asm volatile("s_waitcnt lgkmcnt(0)" ::: "memory");
  __builtin_amdgcn_s_barrier();
  asm volatile("" ::: "memory");
}

// Problem constants
#define BATCH 512
#define TS 1023          // T-1
#define NF 64
#define NS 128
#define NH 128
#define NG 384           // 3H
#define NC 192           // F + SNN
#define TCH 341          // t-chunk for xproj/gru; M per chunk = 341*512 = 1364*128
// All big tensors are t-major: tensor[t][b][feat], flat row m = t*512 + b.

// ---------------- P: weight bf16 conversion ----------------
__global__ void k_prep(const float* __restrict__ wih, const float* __restrict__ w1,
                       u16* __restrict__ wihb, u16* __restrict__ w1b) {
  int i = blockIdx.x * 256 + threadIdx.x;
  if (i < NG * NC) wihb[i] = f2bf(wih[i]);
  if (i < 64 * NH) w1b[i] = f2bf(w1[i]);
}

// ---------------- FRONT: fused delta-GEMM (bf16 hi/lo MFMA) + SNN scan + raw ----------------
// One block per batch b (512 blocks, 256 threads). Streams t in 16 tiles of 64.
// R7: B fragments in registers; A fragments direct from global; LDS = hst only -> 2 blocks/CU.
// R8: barriers are LDS-only (no vmcnt drain of the P5 global store-acks).
__global__ __launch_bounds__(256, 2) void k_front(const float* __restrict__ x,
                                                  const float* __restrict__ pw,
                                                  const float* __restrict__ pb,
                                                  const float* __restrict__ beta1,
                                                  const float* __restrict__ beta2,
                                                  u16* __restrict__ hcomb) {
  __shared__ float hst[64 * 138];                   // 35,328 B (pad 138: quad-writes 2-way free)
  const int tid = threadIdx.x, lane = tid & 63, w = tid >> 6;
  const int m16 = lane & 15, quad = lane >> 4;
  const int b = blockIdx.x;
  const float* xb = x + (long)b * 65536;

  const int tm = (w >> 1) * 32, nn = (w & 1) * 64;

  // B fragments (pw hi/lo) in registers: lane (m16,quad) holds pw[nn+ni*16+m16][kc*32+quad*8 .. +8]
  short8 bh[2][4], bl[2][4];
  #pragma unroll
  for (int kc = 0; kc < 2; ++kc)
    #pragma unroll
    for (int ni = 0; ni < 4; ++ni) {
      const float* src = pw + (nn + ni * 16 + m16) * 64 + kc * 32 + quad * 8;
      f32x4 v0 = *(const f32x4*)src;
      f32x4 v1 = *(const f32x4*)(src + 4);
      #pragma unroll
      for (int jj = 0; jj < 8; ++jj) {
        float v = (jj < 4) ? v0[jj & 3] : v1[jj & 3];
        u16 hh = truncbf(v);
        bh[kc][ni][jj] = (short)hh;
        bl[kc][ni][jj] = (short)f2bf(v - bf2f(hh));
      }
    }

  float b1v = 0.f, b2v = 0.f, m1 = 0.f, s1 = 0.f, m2 = 0.f, s2 = 0.f;
  if (tid < 128) {
    b1v = fminf(fmaxf(beta1[tid], 0.f), 0.99f);
    b2v = fminf(fmaxf(beta2[tid], 0.f), 0.99f);
  }
  float pbv[4];
  #pragma unroll
  for (int ni = 0; ni < 4; ++ni) pbv[ni] = pb[nn + ni * 16 + m16];

  for (int tile = 0; tile < 16; ++tile) {
    const int t0 = tile * 64;
    const int tl = (TS - t0 < 64) ? (TS - t0) : 64;       // 64, last tile 63

    // P3: A fragments direct from global (delta hi/lo on the fly) + MFMA 3-pass
    f32x4 acc[2][4] = {};
    #pragma unroll
    for (int kc = 0; kc < 2; ++kc) {
      short8 ah[2], al[2];
      #pragma unroll
      for (int mi = 0; mi < 2; ++mi) {
        int row = tm + mi * 16 + m16;
        int tA = t0 + row; if (tA > 1022) tA = 1022;      // dead row of last tile, discarded below
        const float* p0 = xb + (long)tA * 64 + kc * 32 + quad * 8;
        f32x4 lo0 = *(const f32x4*)p0;
        f32x4 lo1 = *(const f32x4*)(p0 + 4);
        f32x4 hi0 = *(const f32x4*)(p0 + 64);
        f32x4 hi1 = *(const f32x4*)(p0 + 68);
        float d[8];
        #pragma unroll
        for (int jj = 0; jj < 4; ++jj) { d[jj] = hi0[jj] - lo0[jj]; d[4 + jj] = hi1[jj] - lo1[jj]; }
        #pragma unroll
        for (int jj = 0; jj < 8; ++jj) {
          u16 hh = truncbf(d[jj]);
          ah[mi][jj] = (short)hh;
          al[mi][jj] = (short)f2bf(d[jj] - bf2f(hh));
        }
      }
      #pragma unroll
      for (int mi = 0; mi < 2; ++mi)
        #pragma unroll
        for (int ni = 0; ni < 4; ++ni) {
          acc[mi][ni] = __builtin_amdgcn_mfma_f32_16x16x32_bf16(ah[mi], bh[kc][ni], acc[mi][ni], 0, 0, 0);
          acc[mi][ni] = __builtin_amdgcn_mfma_f32_16x16x32_bf16(ah[mi], bl[kc][ni], acc[mi][ni], 0, 0, 0);
          acc[mi][ni] = __builtin_amdgcn_mfma_f32_16x16x32_bf16(al[mi], bh[kc][ni], acc[mi][ni], 0, 0, 0);
        }
    }
    // P4: hst[t][n] = acc + proj_b (C/D layout: col=lane&15, row=quad*4+reg)
    #pragma unroll
    for (int mi = 0; mi < 2; ++mi)
      #pragma unroll
      for (int ni = 0; ni < 4; ++ni)
        #pragma unroll
        for (int rr = 0; rr < 4; ++rr)
          hst[(tm + mi * 16 + quad * 4 + rr) * 138 + nn + ni * 16 + m16] = acc[mi][ni][rr] + pbv[ni];
    bar_lds();
    // P5: SNN scan (threads 0..127) + raw emit (threads 128..255, reads global directly)
    if (tid < 128) {
      const int n = tid;
      u16* dst = hcomb + ((long)t0 * 512 + b) * NC + 64 + n;
      for (int tt = 0; tt < tl; tt += 8) {
        float v[8];
        #pragma unroll
        for (int jj = 0; jj < 8; ++jj) {
          int t = tt + jj; if (t > 63) t = 63;
          v[jj] = hst[t * 138 + n];
        }
        #pragma unroll
        for (int jj = 0; jj < 8; ++jj) {
          int t = tt + jj;
          if (t < tl) {
            m1 = b1v * m1 + v[jj] - s1;
            s1 = (m1 > 1.0f) ? 1.0f : 0.0f;
            m2 = b2v * m2 + s1 - s2;
            s2 = (m2 > 1.0f) ? 1.0f : 0.0f;
            dst[(long)t * (512 * NC)] = f2bf(m2);
          }
        }
      }
    } else {
      const int f = tid & 63, half = (tid >> 6) & 1;
      for (int r = half; r < tl; r += 2)
        hcomb[((long)(t0 + r) * 512 + b) * NC + f] = f2bf(xb[(long)(t0 + r + 1) * 64 + f]);
    }
    bar_lds();
  }
}

// ---------------- C: x_proj chunk = h_comb @ W_ih^T + b_ih (bf16 MFMA) ----------------
// grid (1364, 3), block 256. BM=128 BN=128 BK=32, 6 k-chunks. hc/xp are chunk-base pointers.
__global__ __launch_bounds__(256) void k_xproj(const u16* __restrict__ hc, const u16* __restrict__ wih,
                                               const float* __restrict__ bih, u16* __restrict__ xp) {
  __shared__ alignas(16) u16 As[4096], Bs[4096];   // 8KB each: 128 rows x 32 bf16 (64B rows)
  const int tid = threadIdx.x, lane = tid & 63, w = tid >> 6;
  const int m16 = lane & 15, quad = lane >> 4;
  const long row0 = (long)blockIdx.x * 128;
  const int n0 = blockIdx.y * 128;
  const int wm = (w >> 1) * 64, wn = (w & 1) * 64;
  f32x4 acc[4][4] = {};
  const char* gA = (const char*)hc + (row0 + (lane >> 2)) * (NC * 2) + (lane & 3) * 16;
  const char* gB = (const char*)wih + (long)(n0 + (lane >> 2)) * (NC * 2) + (lane & 3) * 16;
  for (int kc = 0; kc < 6; ++kc) {
    #pragma unroll
    for (int i = 0; i < 2; ++i) {
      int q = i * 4 + w;
      gll16(gA + (long)q * 16 * (NC * 2) + kc * 64, (char*)As + q * 1024);
      gll16(gB + (long)q * 16 * (NC * 2) + kc * 64, (char*)Bs + q * 1024);
    }
    __syncthreads();
    short8 af[4], bfr[4];
    #pragma unroll
    for (int mi = 0; mi < 4; ++mi) af[mi] = *(const short8*)((const char*)As + (wm + mi * 16 + m16) * 64 + quad * 16);
    #pragma unroll
    for (int ni = 0; ni < 4; ++ni) bfr[ni] = *(const short8*)((const char*)Bs + (wn + ni * 16 + m16) * 64 + quad * 16);
    #pragma unroll
    for (int mi = 0; mi < 4; ++mi)
      #pragma unroll
      for (int ni = 0; ni < 4; ++ni)
        acc[mi][ni] = __builtin_amdgcn_mfma_f32_16x16x32_bf16(af[mi], bfr[ni], acc[mi][ni], 0, 0, 0);
    __syncthreads();
  }
  #pragma unroll
  for (int ni = 0; ni < 4; ++ni) {
    int n = n0 + wn + ni * 16 + m16;
    float bias = bih[n];
    #pragma unroll
    for (int mi = 0; mi < 4; ++mi) {
      long r = row0 + wm + mi * 16 + quad * 4;
      #pragma unroll
      for (int rr = 0; rr < 4; ++rr)
        xp[(r + rr) * NG + n] = f2bf(acc[mi][ni][rr] + bias);
    }
  }
}

// ---------------- D: GRU scan — R10: 1 batch/block, 512 blocks -> 2 co-resident blocks/CU ------
// Same step math/layout as the proven 2-batch version; the two quad-halves (bq=0/1) now
// redundantly compute the SAME batch (A rows 0,8 and 4,12 hold identical h; D rows 0/4/8/12 all
// yield this batch's gh). Duplicate global stores guarded to bq==0; duplicate loads coalesce.
// 2 blocks/CU = 2 waves/SIMD: the co-resident block's issue fills this block's latency stalls
// (ds_read ~120cy, MFMA dep-latency, sigmoid chain, barrier skew).
__global__ __launch_bounds__(256, 1) void k_gru(const u16* __restrict__ xp, const float* __restrict__ whh,
                                                const float* __restrict__ bhh, u16* __restrict__ gout,
                                                float* __restrict__ h_state, int first) {
  __shared__ alignas(16) u16 frag[2 * 2048];   // two 4KB A-fragment ping-pong buffers
  const int tid = threadIdx.x, lane = tid & 63, w = tid >> 6;
  const int m16 = lane & 15, quad = lane >> 4;
  // zero both buffers (invalid A rows harmless for D rows we read, but keep deterministic)
  {
    short8 z8 = {};
    *(short8*)((char*)frag + tid * 16) = z8;
    *(short8*)((char*)frag + 4096 + tid * 16) = z8;
  }
  // W_hh fragments: tile nt = g*2+hh -> B rows g*128 + 32w + hh*16 + m16, k = c*32 + quad*8 + i
  short8 wf[6][4];
  #pragma unroll
  for (int g = 0; g < 3; ++g)
    #pragma unroll
    for (int hh = 0; hh < 2; ++hh)
      #pragma unroll
      for (int c = 0; c < 4; ++c) {
        const float* src = whh + (long)(g * 128 + 32 * w + hh * 16 + m16) * NH + c * 32 + quad * 8;
        short8 v;
        #pragma unroll
        for (int jj = 0; jj < 8; ++jj) v[jj] = (short)f2bf(src[jj]);
        wf[g * 2 + hh][c] = v;
      }
  const int bq = quad & 1, hq = quad >> 1;
  const int j = 32 * w + hq * 16 + m16;        // this lane's j
  const long brow = blockIdx.x;                // one batch per block
  const float br_ = bhh[j], bz_ = bhh[128 + j], bn_ = bhh[256 + j];
  float h = first ? 0.f : h_state[brow * NH + j];
  // frag byte addr for A[m=4*bq][k=j] (c = j>>5 = w): second copy at m+8 -> +128 bytes
  const int fragoff = w * 1024 + 64 * bq + 256 * (hq * 2 + (m16 >> 3)) + 2 * (m16 & 7);
  __syncthreads();                             // zero-init visible
  {
    u16 hb0 = f2bf(h);
    *(u16*)((char*)frag + fragoff) = hb0;
    *(u16*)((char*)frag + fragoff + 128) = hb0;
  }
  const u16* xbase = xp + brow * NG + j;       // + t*512*NG; gates at +0,+128,+256
  u16 pr[8], pz[8], pn[8], sbuf[8];
  #pragma unroll
  for (int u = 0; u < 8; ++u) {
    const u16* xr = xbase + (long)u * (512 * NG);
    pr[u] = xr[0]; pz[u] = xr[128]; pn[u] = xr[256];
  }
  __syncthreads();

#define GRU_STEP(T, U)                                                                     \
  {                                                                                        \
    const int cur = ((T) & 1) * 4096, nxt = 4096 - cur;                                    \
    short8 af[4];                                                                          \
    _Pragma("unroll")                                                                      \
    for (int c = 0; c < 4; ++c)                                                            \
      af[c] = *(const short8*)((const char*)frag + cur + c * 1024 + lane * 16);            \
    f32x4 zero = {0.f, 0.f, 0.f, 0.f};                                                     \
    f32x4 accA[6], accB[6];                                                                \
    _Pragma("unroll")                                                                      \
    for (int nt = 0; nt < 6; ++nt) {                                                       \
      accA[nt] = __builtin_amdgcn_mfma_f32_16x16x32_bf16(af[0], wf[nt][0], zero, 0, 0, 0); \
      accB[nt] = __builtin_amdgcn_mfma_f32_16x16x32_bf16(af[2], wf[nt][2], zero, 0, 0, 0); \
    }                                                                                      \
    _Pragma("unroll")                                                                      \
    for (int nt = 0; nt < 6; ++nt) {                                                       \
      accA[nt] = __builtin_amdgcn_mfma_f32_16x16x32_bf16(af[1], wf[nt][1], accA[nt], 0, 0, 0); \
      accB[nt] = __builtin_amdgcn_mfma_f32_16x16x32_bf16(af[3], wf[nt][3], accB[nt], 0, 0, 0); \
    }                                                                                      \
    float ghr = (hq ? (accA[1][0] + accB[1][0]) : (accA[0][0] + accB[0][0])) + br_;        \
    float ghz = (hq ? (accA[3][0] + accB[3][0]) : (accA[2][0] + accB[2][0])) + bz_;        \
    float ghn = (hq ? (accA[5][0] + accB[5][0]) : (accA[4][0] + accB[4][0])) + bn_;        \
    float xrv = bf2f(pr[U]), xzv = bf2f(pz[U]), xnv = bf2f(pn[U]);                         \
    float rg = 1.f / (1.f + __expf(-(xrv + ghr)));                                         \
    float zg = 1.f / (1.f + __expf(-(xzv + ghz)));                                         \
    float niv = xnv + rg * ghn;                                                            \
    float ng = 1.f - 2.f / (1.f + __expf(2.f * niv));                                      \
    h = (1.f - zg) * ng + zg * h;                                                          \
    u16 hb = f2bf(h);                                                                      \
    sbuf[U] = hb;                                                                          \
    *(u16*)((char*)frag + nxt + fragoff) = hb;                                             \
    *(u16*)((char*)frag + nxt + fragoff + 128) = hb;                                       \
    __syncthreads();                                                                       \
  }

  for (int t8 = 0; t8 < 336; t8 += 8) {
    // flush previous group's stores (none on first group); bq==0 half only (bq==1 is duplicate)
    if (t8 > 0 && bq == 0) {
      #pragma unroll
      for (int u = 0; u < 8; ++u)
        gout[((long)(t8 - 8 + u) * 512 + brow) * NH + j] = sbuf[u];
    }
    // prefetch next group's xp (t8+8 .. t8+15, clamped); dup addresses coalesce in-wave
    u16 npr[8], npz[8], npn[8];
    #pragma unroll
    for (int u = 0; u < 8; ++u) {
      long tp = t8 + 8 + u; if (tp > TCH - 1) tp = TCH - 1;
      const u16* xr = xbase + tp * (512 * NG);
      npr[u] = xr[0]; npz[u] = xr[128]; npn[u] = xr[256];
    }
    GRU_STEP(t8 + 0, 0) GRU_STEP(t8 + 1, 1) GRU_STEP(t8 + 2, 2) GRU_STEP(t8 + 3, 3)
    GRU_STEP(t8 + 4, 4) GRU_STEP(t8 + 5, 5) GRU_STEP(t8 + 6, 6) GRU_STEP(t8 + 7, 7)
    #pragma unroll
    for (int u = 0; u < 8; ++u) { pr[u] = npr[u]; pz[u] = npz[u]; pn[u] = npn[u]; }
  }
  // flush group t=328..335
  if (bq == 0) {
    #pragma unroll
    for (int u = 0; u < 8; ++u)
      gout[((long)(328 + u) * 512 + brow) * NH + j] = sbuf[u];
  }
  // tail t = 336..340 (pre holds them), store immediately
  #pragma unroll
  for (int u = 0; u < 5; ++u) {
    GRU_STEP(336 + u, u)
    if (bq == 0) gout[((long)(336 + u) * 512 + brow) * NH + j] = sbuf[u];
  }
#undef GRU_STEP
  if (bq == 0) h_state[brow * NH + j] = h;
}

// ---------------- E: scores = relu(gru@W1^T + b1)@w2 + b2 (bf16 MFMA, fused 2nd layer) ----------------
// grid 4092, block 256. BM=128, BN=64, K=128 (4 chunks). M-rows = t*512+b (t-major).
__global__ __launch_bounds__(256) void k_score(const u16* __restrict__ gbf, const u16* __restrict__ w1,
                                               const float* __restrict__ b1, const float* __restrict__ w2,
                                               const float* __restrict__ b2, float* __restrict__ scores) {
  __shared__ alignas(16) u16 Gs[4096], Ws[2048];
  const int tid = threadIdx.x, lane = tid & 63, w = tid >> 6;
  const int m16 = lane & 15, quad = lane >> 4;
  const long row0 = (long)blockIdx.x * 128;
  f32x4 acc[2][4] = {};
  const char* gG = (const char*)gbf + (row0 + (lane >> 2)) * (NH * 2) + (lane & 3) * 16;
  const char* gW = (const char*)w1 + (long)(w * 16 + (lane >> 2)) * (NH * 2) + (lane & 3) * 16;
  for (int kc = 0; kc < 4; ++kc) {
    #pragma unroll
    for (int i = 0; i < 2; ++i) {
      int q = i * 4 + w;
      gll16(gG + (long)q * 16 * (NH * 2) + kc * 64, (char*)Gs + q * 1024);
    }
    gll16(gW + kc * 64, (char*)Ws + w * 1024);
    __syncthreads();
    short8 af[2], bfr[4];
    #pragma unroll
    for (int mi = 0; mi < 2; ++mi) af[mi] = *(const short8*)((const char*)Gs + (w * 32 + mi * 16 + m16) * 64 + quad * 16);
    #pragma unroll
    for (int ni = 0; ni < 4; ++ni) bfr[ni] = *(const short8*)((const char*)Ws + (ni * 16 + m16) * 64 + quad * 16);
    #pragma unroll
    for (int mi = 0; mi < 2; ++mi)
      #pragma unroll
      for (int ni = 0; ni < 4; ++ni)
        acc[mi][ni] = __builtin_amdgcn_mfma_f32_16x16x32_bf16(af[mi], bfr[ni], acc[mi][ni], 0, 0, 0);
    __syncthreads();
  }
  float b2v = b2[0];
  float w2v[4], b1v[4];
  #pragma unroll
  for (int ni = 0; ni < 4; ++ni) { w2v[ni] = w2[ni * 16 + m16]; b1v[ni] = b1[ni * 16 + m16]; }
  #pragma unroll
  for (int mi = 0; mi < 2; ++mi) {
    #pragma unroll
    for (int rr = 0; rr < 4; ++rr) {
      float v = 0.f;
      #pragma unroll
      for (int ni = 0; ni < 4; ++ni) {
        float hv = acc[mi][ni][rr] + b1v[ni];
        hv = hv > 0.f ? hv : 0.f;
        v = fmaf(hv, w2v[ni], v);
      }
      v += __shfl_xor(v, 1, 64); v += __shfl_xor(v, 2, 64);
      v += __shfl_xor(v, 4, 64); v += __shfl_xor(v, 8, 64);
      if (m16 == 0) scores[row0 + w * 32 + mi * 16 + quad * 4 + rr] = v + b2v;
    }
  }
}

// ---------------- F: softmax over t + weighted sum + head ----------------
// 512 blocks (one per batch) x 256 threads. scores/gout are t-major.
__global__ __launch_bounds__(256) void k_attn(const float* __restrict__ scores, const u16* __restrict__ gout,
                                              const float* __restrict__ headw, const float* __restrict__ headb,
                                              float* __restrict__ out) {
  __shared__ float sc[TS];
  __shared__ float red[8];
  __shared__ float part[8][132];
  __shared__ float hann[128];
  const int tid = threadIdx.x, lane = tid & 63, w = tid >> 6;
  const long b = blockIdx.x;
  const float* srow = scores + b;        // stride 512 per t
  float s0[4];
  #pragma unroll
  for (int i = 0; i < 4; ++i) {
    int t = tid + i * 256;
    s0[i] = (t < TS) ? srow[(long)t * 512] : -1e30f;
  }
  float mx = fmaxf(fmaxf(s0[0], s0[1]), fmaxf(s0[2], s0[3]));
  #pragma unroll
  for (int off = 32; off > 0; off >>= 1) mx = fmaxf(mx, __shfl_xor(mx, off, 64));
  if (lane == 0) red[w] = mx;
  __syncthreads();
  mx = fmaxf(fmaxf(red[0], red[1]), fmaxf(red[2], red[3]));
  float sum = 0.f;
  #pragma unroll
  for (int i = 0; i < 4; ++i) {
    int t = tid + i * 256;
    if (t < TS) { float e = __expf(s0[i] - mx); sc[t] = e; sum += e; }
  }
  #pragma unroll
  for (int off = 32; off > 0; off >>= 1) sum += __shfl_xor(sum, off, 64);
  if (lane == 0) red[4 + w] = sum;
  __syncthreads();
  float inv = 1.f / (red[4] + red[5] + red[6] + red[7]);
  const int jg = tid & 31, sl = tid >> 5;
  float acc[4] = {0.f, 0.f, 0.f, 0.f};
  const u16* gbase = gout + b * NH + jg * 4;   // stride 512*NH per t
  for (int t = sl; t < TS; t += 8) {
    float wt = sc[t];
    ushort4 g4 = *(const ushort4*)(gbase + (long)t * (512 * NH));
    acc[0] = fmaf(wt, bf2f(g4.x), acc[0]);
    acc[1] = fmaf(wt, bf2f(g4.y), acc[1]);
    acc[2] = fmaf(wt, bf2f(g4.z), acc[2]);
    acc[3] = fmaf(wt, bf2f(g4.w), acc[3]);
  }
  #pragma unroll
  for (int i = 0; i < 4; ++i) part[sl][jg * 4 + i] = acc[i];
  __syncthreads();
  if (tid < 128) {
    float v = 0.f;
    #pragma unroll
    for (int s = 0; s < 8; ++s) v += part[s][tid];
    hann[tid] = v * inv;
  }
  __syncthreads();
  if (tid < 24) {
    float a = headb[tid];
    const float* hwr = headw + tid * 128;
    for (int k = 0; k < 128; k += 4) {
      float4 h4 = *(const float4*)&hann[k];
      float4 w4 = *(const float4*)&hwr[k];
      a = fmaf(h4.x, w4.x, a); a = fmaf(h4.y, w4.y, a);
      a = fmaf(h4.z, w4.z, a); a = fmaf(h4.w, w4.w, a);
    }
    out[b * 24 + tid] = a;
  }
}

extern "C" void kernel_launch(void* const* d_in, const int* in_sizes, int n_in,
                              void* d_out, int out_size, void* d_ws, size_t ws_size,
                              hipStream_t stream) {
  const float* x      = (const float*)d_in[0];
  const float* proj_w = (const float*)d_in[1];
  const float* proj_b = (const float*)d_in[2];
  const float* beta1  = (const float*)d_in[3];
  const float* beta2  = (const float*)d_in[4];
  const float* gwih   = (const float*)d_in[5];
  const float* gwhh   = (const float*)d_in[6];
  const float* gbih   = (const float*)d_in[7];
  const float* gbhh   = (const float*)d_in[8];
  const float* aw1    = (const float*)d_in[9];
  const float* ab1    = (const float*)d_in[10];
  const float* aw2    = (const float*)d_in[11];
  const float* ab2    = (const float*)d_in[12];
  const float* hw     = (const float*)d_in[13];
  const float* hb     = (const float*)d_in[14];
  float* out = (float*)d_out;
  char* ws = (char*)d_ws;

  // Workspace (bytes) — same envelope as R2..R6 (proven to fit):
  u16*   hcomb  = (u16*)(ws);
  u16*   xpbuf  = (u16*)(ws + 201129984L);
  u16*   gru    = (u16*)(ws + 335216640L);
  float* scores = (float*)(ws + 469303296L);
  u16*   wihb   = (u16*)(ws + 471398400L);
  u16*   w1b    = (u16*)(ws + 471545856L);
  float* hstate = (float*)(ws + 471562240L);

  k_prep<<<288, 256, 0, stream>>>(gwih, aw1, wihb, w1b);
  k_front<<<512, 256, 0, stream>>>(x, proj_w, proj_b, beta1, beta2, hcomb);
  for (int c = 0; c < 3; ++c) {
    long rowbase = (long)c * TCH * 512;
    k_xproj<<<dim3(1364, 3), 256, 0, stream>>>(hcomb + rowbase * NC, wihb, gbih, xpbuf);
    k_gru<<<512, 256, 0, stream>>>(xpbuf, gwhh, gbhh, gru + rowbase * NH, hstate, c == 0 ? 1 : 0);
  }
  k_score<<<4092, 256, 0, stream>>>(gru, w1b, ab1, aw2, ab2, scores);
  k_attn<<<512, 256, 0, stream>>>(scores, gru, hw, hb, out);
}

// Round 5
// 1069.337 us; speedup vs baseline: 1.4278x; 1.4278x over previous
//
#include <hip/hip_runtime.h>

typedef unsigned short u16;
typedef __attribute__((ext_vector_type(8))) short short8;
typedef __attribute__((ext_vector_type(4))) float f32x4;

__device__ __forceinline__ u16 f2bf(float f) {
  union { float f; unsigned u; } v; v.f = f;
  unsigned r = v.u + 0x7fffu + ((v.u >> 16) & 1u);
  return (u16)(r >> 16);
}
__device__ __forceinline__ u16 truncbf(float f) {
  union { float f; unsigned u; } v; v.f = f;
  return (u16)(v.u >> 16);
}
__device__ __forceinline__ float bf2f(u16 h) {
  union { unsigned u; float f; } v; v.u = ((unsigned)h) << 16;
  return v.f;
}
// async global->LDS, 16B per lane; LDS dest = wave-uniform base (HW adds lane*16), 16B aligned
__device__ __forceinline__ void gll16(const void* g, void* l) {
  __builtin_amdgcn_global_load_lds((const __attribute__((address_space(1))) unsigned*)g,
                                   (__attribute__((address_space(3))) unsigned*)l, 16, 0, 0);
}
// Workgroup barrier that orders LDS only (no vmcnt drain). Used in k_front only (proven win);
// k_gru keeps __syncthreads (R8 confounded; gru step stays byte-identical to the 177us version).
__device__ __forceinline__ void bar_lds() {
  asm volatile("s_waitcnt lgkmcnt(0)" ::: "memory");
  __builtin_amdgcn_s_barrier();
  asm volatile("" ::: "memory");
}

// Problem constants
#define BATCH 512
#define TS 1023          // T-1
#define NF 64
#define NS 128
#define NH 128
#define NG 384           // 3H
#define NC 192           // F + SNN
#define TCH 341          // t-chunk for xproj/gru; M per chunk = 341*512 = 1364*128
// All big tensors are t-major: tensor[t][b][feat], flat row m = t*512 + b.

// ---------------- P: weight bf16 conversion ----------------
__global__ void k_prep(const float* __restrict__ wih, const float* __restrict__ w1,
                       u16* __restrict__ wihb, u16* __restrict__ w1b) {
  int i = blockIdx.x * 256 + threadIdx.x;
  if (i < NG * NC) wihb[i] = f2bf(wih[i]);
  if (i < 64 * NH) w1b[i] = f2bf(w1[i]);
}

// ---------------- FRONT: fused delta-GEMM (bf16 hi/lo MFMA) + SNN scan + raw ----------------
// One block per batch b (512 blocks, 256 threads). Streams t in 16 tiles of 64.
// R7: B fragments in registers; A fragments direct from global; LDS = hst only -> 2 blocks/CU.
// R8: barriers are LDS-only (no vmcnt drain of the P5 global store-acks).
__global__ __launch_bounds__(256, 2) void k_front(const float* __restrict__ x,
                                                  const float* __restrict__ pw,
                                                  const float* __restrict__ pb,
                                                  const float* __restrict__ beta1,
                                                  const float* __restrict__ beta2,
                                                  u16* __restrict__ hcomb) {
  __shared__ float hst[64 * 138];                   // 35,328 B (pad 138: quad-writes 2-way free)
  const int tid = threadIdx.x, lane = tid & 63, w = tid >> 6;
  const int m16 = lane & 15, quad = lane >> 4;
  const int b = blockIdx.x;
  const float* xb = x + (long)b * 65536;

  const int tm = (w >> 1) * 32, nn = (w & 1) * 64;

  // B fragments (pw hi/lo) in registers: lane (m16,quad) holds pw[nn+ni*16+m16][kc*32+quad*8 .. +8]
  short8 bh[2][4], bl[2][4];
  #pragma unroll
  for (int kc = 0; kc < 2; ++kc)
    #pragma unroll
    for (int ni = 0; ni < 4; ++ni) {
      const float* src = pw + (nn + ni * 16 + m16) * 64 + kc * 32 + quad * 8;
      f32x4 v0 = *(const f32x4*)src;
      f32x4 v1 = *(const f32x4*)(src + 4);
      #pragma unroll
      for (int jj = 0; jj < 8; ++jj) {
        float v = (jj < 4) ? v0[jj & 3] : v1[jj & 3];
        u16 hh = truncbf(v);
        bh[kc][ni][jj] = (short)hh;
        bl[kc][ni][jj] = (short)f2bf(v - bf2f(hh));
      }
    }

  float b1v = 0.f, b2v = 0.f, m1 = 0.f, s1 = 0.f, m2 = 0.f, s2 = 0.f;
  if (tid < 128) {
    b1v = fminf(fmaxf(beta1[tid], 0.f), 0.99f);
    b2v = fminf(fmaxf(beta2[tid], 0.f), 0.99f);
  }
  float pbv[4];
  #pragma unroll
  for (int ni = 0; ni < 4; ++ni) pbv[ni] = pb[nn + ni * 16 + m16];

  for (int tile = 0; tile < 16; ++tile) {
    const int t0 = tile * 64;
    const int tl = (TS - t0 < 64) ? (TS - t0) : 64;       // 64, last tile 63

    // P3: A fragments direct from global (delta hi/lo on the fly) + MFMA 3-pass
    f32x4 acc[2][4] = {};
    #pragma unroll
    for (int kc = 0; kc < 2; ++kc) {
      short8 ah[2], al[2];
      #pragma unroll
      for (int mi = 0; mi < 2; ++mi) {
        int row = tm + mi * 16 + m16;
        int tA = t0 + row; if (tA > 1022) tA = 1022;      // dead row of last tile, discarded below
        const float* p0 = xb + (long)tA * 64 + kc * 32 + quad * 8;
        f32x4 lo0 = *(const f32x4*)p0;
        f32x4 lo1 = *(const f32x4*)(p0 + 4);
        f32x4 hi0 = *(const f32x4*)(p0 + 64);
        f32x4 hi1 = *(const f32x4*)(p0 + 68);
        float d[8];
        #pragma unroll
        for (int jj = 0; jj < 4; ++jj) { d[jj] = hi0[jj] - lo0[jj]; d[4 + jj] = hi1[jj] - lo1[jj]; }
        #pragma unroll
        for (int jj = 0; jj < 8; ++jj) {
          u16 hh = truncbf(d[jj]);
          ah[mi][jj] = (short)hh;
          al[mi][jj] = (short)f2bf(d[jj] - bf2f(hh));
        }
      }
      #pragma unroll
      for (int mi = 0; mi < 2; ++mi)
        #pragma unroll
        for (int ni = 0; ni < 4; ++ni) {
          acc[mi][ni] = __builtin_amdgcn_mfma_f32_16x16x32_bf16(ah[mi], bh[kc][ni], acc[mi][ni], 0, 0, 0);
          acc[mi][ni] = __builtin_amdgcn_mfma_f32_16x16x32_bf16(ah[mi], bl[kc][ni], acc[mi][ni], 0, 0, 0);
          acc[mi][ni] = __builtin_amdgcn_mfma_f32_16x16x32_bf16(al[mi], bh[kc][ni], acc[mi][ni], 0, 0, 0);
        }
    }
    // P4: hst[t][n] = acc + proj_b (C/D layout: col=lane&15, row=quad*4+reg)
    #pragma unroll
    for (int mi = 0; mi < 2; ++mi)
      #pragma unroll
      for (int ni = 0; ni < 4; ++ni)
        #pragma unroll
        for (int rr = 0; rr < 4; ++rr)
          hst[(tm + mi * 16 + quad * 4 + rr) * 138 + nn + ni * 16 + m16] = acc[mi][ni][rr] + pbv[ni];
    bar_lds();
    // P5: SNN scan (threads 0..127) + raw emit (threads 128..255, reads global directly)
    if (tid < 128) {
      const int n = tid;
      u16* dst = hcomb + ((long)t0 * 512 + b) * NC + 64 + n;
      for (int tt = 0; tt < tl; tt += 8) {
        float v[8];
        #pragma unroll
        for (int jj = 0; jj < 8; ++jj) {
          int t = tt + jj; if (t > 63) t = 63;
          v[jj] = hst[t * 138 + n];
        }
        #pragma unroll
        for (int jj = 0; jj < 8; ++jj) {
          int t = tt + jj;
          if (t < tl) {
            m1 = b1v * m1 + v[jj] - s1;
            s1 = (m1 > 1.0f) ? 1.0f : 0.0f;
            m2 = b2v * m2 + s1 - s2;
            s2 = (m2 > 1.0f) ? 1.0f : 0.0f;
            dst[(long)t * (512 * NC)] = f2bf(m2);
          }
        }
      }
    } else {
      const int f = tid & 63, half = (tid >> 6) & 1;
      for (int r = half; r < tl; r += 2)
        hcomb[((long)(t0 + r) * 512 + b) * NC + f] = f2bf(xb[(long)(t0 + r + 1) * 64 + f]);
    }
    bar_lds();
  }
}

// ---------------- C: x_proj chunk = h_comb @ W_ih^T + b_ih (bf16 MFMA) ----------------
// grid (1364, 3), block 256. BM=128 BN=128 BK=32, 6 k-chunks. hc/xp are chunk-base pointers.
__global__ __launch_bounds__(256) void k_xproj(const u16* __restrict__ hc, const u16* __restrict__ wih,
                                               const float* __restrict__ bih, u16* __restrict__ xp) {
  __shared__ alignas(16) u16 As[4096], Bs[4096];   // 8KB each: 128 rows x 32 bf16 (64B rows)
  const int tid = threadIdx.x, lane = tid & 63, w = tid >> 6;
  const int m16 = lane & 15, quad = lane >> 4;
  const long row0 = (long)blockIdx.x * 128;
  const int n0 = blockIdx.y * 128;
  const int wm = (w >> 1) * 64, wn = (w & 1) * 64;
  f32x4 acc[4][4] = {};
  const char* gA = (const char*)hc + (row0 + (lane >> 2)) * (NC * 2) + (lane & 3) * 16;
  const char* gB = (const char*)wih + (long)(n0 + (lane >> 2)) * (NC * 2) + (lane & 3) * 16;
  for (int kc = 0; kc < 6; ++kc) {
    #pragma unroll
    for (int i = 0; i < 2; ++i) {
      int q = i * 4 + w;
      gll16(gA + (long)q * 16 * (NC * 2) + kc * 64, (char*)As + q * 1024);
      gll16(gB + (long)q * 16 * (NC * 2) + kc * 64, (char*)Bs + q * 1024);
    }
    __syncthreads();
    short8 af[4], bfr[4];
    #pragma unroll
    for (int mi = 0; mi < 4; ++mi) af[mi] = *(const short8*)((const char*)As + (wm + mi * 16 + m16) * 64 + quad * 16);
    #pragma unroll
    for (int ni = 0; ni < 4; ++ni) bfr[ni] = *(const short8*)((const char*)Bs + (wn + ni * 16 + m16) * 64 + quad * 16);
    #pragma unroll
    for (int mi = 0; mi < 4; ++mi)
      #pragma unroll
      for (int ni = 0; ni < 4; ++ni)
        acc[mi][ni] = __builtin_amdgcn_mfma_f32_16x16x32_bf16(af[mi], bfr[ni], acc[mi][ni], 0, 0, 0);
    __syncthreads();
  }
  #pragma unroll
  for (int ni = 0; ni < 4; ++ni) {
    int n = n0 + wn + ni * 16 + m16;
    float bias = bih[n];
    #pragma unroll
    for (int mi = 0; mi < 4; ++mi) {
      long r = row0 + wm + mi * 16 + quad * 4;
      #pragma unroll
      for (int rr = 0; rr < 4; ++rr)
        xp[(r + rr) * NG + n] = f2bf(acc[mi][ni][rr] + bias);
    }
  }
}

// ---------------- score body: scores = relu(g@W1^T + b1)@w2 + b2 for one 128-row block ----------------
__device__ __forceinline__ void score_body(long row0, const u16* __restrict__ gbf, const u16* __restrict__ w1,
                                           const float* __restrict__ b1, const float* __restrict__ w2,
                                           const float* __restrict__ b2, float* __restrict__ scores,
                                           u16* Gs, u16* Ws) {
  const int tid = threadIdx.x, lane = tid & 63, w = tid >> 6;
  const int m16 = lane & 15, quad = lane >> 4;
  f32x4 acc[2][4] = {};
  const char* gG = (const char*)gbf + (row0 + (lane >> 2)) * (NH * 2) + (lane & 3) * 16;
  const char* gW = (const char*)w1 + (long)(w * 16 + (lane >> 2)) * (NH * 2) + (lane & 3) * 16;
  for (int kc = 0; kc < 4; ++kc) {
    #pragma unroll
    for (int i = 0; i < 2; ++i) {
      int q = i * 4 + w;
      gll16(gG + (long)q * 16 * (NH * 2) + kc * 64, (char*)Gs + q * 1024);
    }
    gll16(gW + kc * 64, (char*)Ws + w * 1024);
    __syncthreads();
    short8 af[2], bfr[4];
    #pragma unroll
    for (int mi = 0; mi < 2; ++mi) af[mi] = *(const short8*)((const char*)Gs + (w * 32 + mi * 16 + m16) * 64 + quad * 16);
    #pragma unroll
    for (int ni = 0; ni < 4; ++ni) bfr[ni] = *(const short8*)((const char*)Ws + (ni * 16 + m16) * 64 + quad * 16);
    #pragma unroll
    for (int mi = 0; mi < 2; ++mi)
      #pragma unroll
      for (int ni = 0; ni < 4; ++ni)
        acc[mi][ni] = __builtin_amdgcn_mfma_f32_16x16x32_bf16(af[mi], bfr[ni], acc[mi][ni], 0, 0, 0);
    __syncthreads();
  }
  float b2v = b2[0];
  float w2v[4], b1v[4];
  #pragma unroll
  for (int ni = 0; ni < 4; ++ni) { w2v[ni] = w2[ni * 16 + m16]; b1v[ni] = b1[ni * 16 + m16]; }
  #pragma unroll
  for (int mi = 0; mi < 2; ++mi) {
    #pragma unroll
    for (int rr = 0; rr < 4; ++rr) {
      float v = 0.f;
      #pragma unroll
      for (int ni = 0; ni < 4; ++ni) {
        float hv = acc[mi][ni][rr] + b1v[ni];
        hv = hv > 0.f ? hv : 0.f;
        v = fmaf(hv, w2v[ni], v);
      }
      v += __shfl_xor(v, 1, 64); v += __shfl_xor(v, 2, 64);
      v += __shfl_xor(v, 4, 64); v += __shfl_xor(v, 8, 64);
      if (m16 == 0) scores[row0 + w * 32 + mi * 16 + quad * 4 + rr] = v + b2v;
    }
  }
}

// ---------------- E: standalone score kernel (chunk 2 tail), grid 1364 ----------------
__global__ __launch_bounds__(256) void k_score(const u16* __restrict__ gbf, const u16* __restrict__ w1,
                                               const float* __restrict__ b1, const float* __restrict__ w2,
                                               const float* __restrict__ b2, float* __restrict__ scores,
                                               long row_base) {
  __shared__ alignas(16) u16 Gs[4096], Ws[2048];
  score_body(row_base + (long)blockIdx.x * 128, gbf, w1, b1, w2, b2, scores, Gs, Ws);
}

// ---------------- D: GRU scan (exact 177us step) + co-resident score blocks ----------------
// Blocks 0..255: GRU, 2 batches/block (proven R7 step, __syncthreads, 24 MFMAs up-front).
// Blocks 256+: score_body for chunk c-1. KEY FIX vs R9: __launch_bounds__(256, 2) — the second
// arg equals workgroups/CU for 256-thread blocks; (256,1) was capping residency at 1 block/CU,
// which is why R9's score blocks ran serially at the tail and R10's 512 blocks ran in 2 rounds.
// With 2 blocks/CU: 1 gru + 1 score co-resident; score fills gru's ~70% idle issue slots.
__global__ __launch_bounds__(256, 2) void k_gru(const u16* __restrict__ xp, const float* __restrict__ whh,
                                                const float* __restrict__ bhh, u16* __restrict__ gout,
                                                float* __restrict__ h_state, int first,
                                                const u16* __restrict__ gbf, const u16* __restrict__ w1,
                                                const float* __restrict__ b1, const float* __restrict__ w2,
                                                const float* __restrict__ b2, float* __restrict__ scores,
                                                long score_base) {
  __shared__ alignas(16) u16 frag[2 * 2048];      // two 4KB A-fragment ping-pong buffers (GRU path)
  __shared__ alignas(16) u16 Gs[4096], Ws[2048];  // score path
  if (blockIdx.x >= 256) {
    score_body(score_base + (long)(blockIdx.x - 256) * 128, gbf, w1, b1, w2, b2, scores, Gs, Ws);
    return;
  }
  const int tid = threadIdx.x, lane = tid & 63, w = tid >> 6;
  const int m16 = lane & 15, quad = lane >> 4;
  const long bg0 = (long)blockIdx.x * 2;
  // zero both buffers (invalid A rows harmless for D rows we read, but keep deterministic)
  {
    short8 z8 = {};
    *(short8*)((char*)frag + tid * 16) = z8;
    *(short8*)((char*)frag + 4096 + tid * 16) = z8;
  }
  // W_hh fragments: tile nt = g*2+hh -> B rows g*128 + 32w + hh*16 + m16, k = c*32 + quad*8 + i
  short8 wf[6][4];
  #pragma unroll
  for (int g = 0; g < 3; ++g)
    #pragma unroll
    for (int hh = 0; hh < 2; ++hh)
      #pragma unroll
      for (int c = 0; c < 4; ++c) {
        const float* src = whh + (long)(g * 128 + 32 * w + hh * 16 + m16) * NH + c * 32 + quad * 8;
        short8 v;
        #pragma unroll
        for (int jj = 0; jj < 8; ++jj) v[jj] = (short)f2bf(src[jj]);
        wf[g * 2 + hh][c] = v;
      }
  const int bq = quad & 1, hq = quad >> 1;
  const int j = 32 * w + hq * 16 + m16;        // this lane's j (all 64 lanes distinct (bq,j))
  const long brow = bg0 + bq;
  const float br_ = bhh[j], bz_ = bhh[128 + j], bn_ = bhh[256 + j];
  float h = first ? 0.f : h_state[brow * NH + j];
  // frag byte addr for A[m=4*bq][k=j] (c = j>>5 = w): second copy at m+8 -> +128 bytes
  const int fragoff = w * 1024 + 64 * bq + 256 * (hq * 2 + (m16 >> 3)) + 2 * (m16 & 7);
  __syncthreads();                             // zero-init visible
  {
    u16 hb0 = f2bf(h);
    *(u16*)((char*)frag + fragoff) = hb0;
    *(u16*)((char*)frag + fragoff + 128) = hb0;
  }
  const u16* xbase = xp + brow * NG + j;       // + t*512*NG; gates at +0,+128,+256
  u16 pr[8], pz[8], pn[8], sbuf[8];
  #pragma unroll
  for (int u = 0; u < 8; ++u) {
    const u16* xr = xbase + (long)u * (512 * NG);
    pr[u] = xr[0]; pz[u] = xr[128]; pn[u] = xr[256];
  }
  __syncthreads();

#define GRU_STEP(T, U)                                                                     \
  {                                                                                        \
    const int cur = ((T) & 1) * 4096, nxt = 4096 - cur;                                    \
    short8 af[4];                                                                          \
    _Pragma("unroll")                                                                      \
    for (int c = 0; c < 4; ++c)                                                            \
      af[c] = *(const short8*)((const char*)frag + cur + c * 1024 + lane * 16);            \
    f32x4 zero = {0.f, 0.f, 0.f, 0.f};                                                     \
    f32x4 accA[6], accB[6];                                                                \
    _Pragma("unroll")                                                                      \
    for (int nt = 0; nt < 6; ++nt) {                                                       \
      accA[nt] = __builtin_amdgcn_mfma_f32_16x16x32_bf16(af[0], wf[nt][0], zero, 0, 0, 0); \
      accB[nt] = __builtin_amdgcn_mfma_f32_16x16x32_bf16(af[2], wf[nt][2], zero, 0, 0, 0); \
    }                                                                                      \
    _Pragma("unroll")                                                                      \
    for (int nt = 0; nt < 6; ++nt) {                                                       \
      accA[nt] = __builtin_amdgcn_mfma_f32_16x16x32_bf16(af[1], wf[nt][1], accA[nt], 0, 0, 0); \
      accB[nt] = __builtin_amdgcn_mfma_f32_16x16x32_bf16(af[3], wf[nt][3], accB[nt], 0, 0, 0); \
    }                                                                                      \
    float ghr = (hq ? (accA[1][0] + accB[1][0]) : (accA[0][0] + accB[0][0])) + br_;        \
    float ghz = (hq ? (accA[3][0] + accB[3][0]) : (accA[2][0] + accB[2][0])) + bz_;        \
    float ghn = (hq ? (accA[5][0] + accB[5][0]) : (accA[4][0] + accB[4][0])) + bn_;        \
    float xrv = bf2f(pr[U]), xzv = bf2f(pz[U]), xnv = bf2f(pn[U]);                         \
    float rg = 1.f / (1.f + __expf(-(xrv + ghr)));                                         \
    float zg = 1.f / (1.f + __expf(-(xzv + ghz)));                                         \
    float niv = xnv + rg * ghn;                                                            \
    float ng = 1.f - 2.f / (1.f + __expf(2.f * niv));                                      \
    h = (1.f - zg) * ng + zg * h;                                                          \
    u16 hb = f2bf(h);                                                                      \
    sbuf[U] = hb;                                                                          \
    *(u16*)((char*)frag + nxt + fragoff) = hb;                                             \
    *(u16*)((char*)frag + nxt + fragoff + 128) = hb;                                       \
    __syncthreads();                                                                       \
  }

  for (int t8 = 0; t8 < 336; t8 += 8) {
    // flush previous group's stores (none on first group)
    if (t8 > 0) {
      #pragma unroll
      for (int u = 0; u < 8; ++u)
        gout[((long)(t8 - 8 + u) * 512 + brow) * NH + j] = sbuf[u];
    }
    // prefetch next group's xp (t8+8 .. t8+15, clamped)
    u16 npr[8], npz[8], npn[8];
    #pragma unroll
    for (int u = 0; u < 8; ++u) {
      long tp = t8 + 8 + u; if (tp > TCH - 1) tp = TCH - 1;
      const u16* xr = xbase + tp * (512 * NG);
      npr[u] = xr[0]; npz[u] = xr[128]; npn[u] = xr[256];
    }
    GRU_STEP(t8 + 0, 0) GRU_STEP(t8 + 1, 1) GRU_STEP(t8 + 2, 2) GRU_STEP(t8 + 3, 3)
    GRU_STEP(t8 + 4, 4) GRU_STEP(t8 + 5, 5) GRU_STEP(t8 + 6, 6) GRU_STEP(t8 + 7, 7)
    #pragma unroll
    for (int u = 0; u < 8; ++u) { pr[u] = npr[u]; pz[u] = npz[u]; pn[u] = npn[u]; }
  }
  // flush group t=328..335
  #pragma unroll
  for (int u = 0; u < 8; ++u)
    gout[((long)(328 + u) * 512 + brow) * NH + j] = sbuf[u];
  // tail t = 336..340 (pre holds them), store immediately
  #pragma unroll
  for (int u = 0; u < 5; ++u) {
    GRU_STEP(336 + u, u)
    gout[((long)(336 + u) * 512 + brow) * NH + j] = sbuf[u];
  }
#undef GRU_STEP
  h_state[brow * NH + j] = h;
}

// ---------------- F: softmax over t + weighted sum + head ----------------
// 512 blocks (one per batch) x 256 threads. scores/gout are t-major.
__global__ __launch_bounds__(256) void k_attn(const float* __restrict__ scores, const u16* __restrict__ gout,
                                              const float* __restrict__ headw, const float* __restrict__ headb,
                                              float* __restrict__ out) {
  __shared__ float sc[TS];
  __shared__ float red[8];
  __shared__ float part[8][132];
  __shared__ float hann[128];
  const int tid = threadIdx.x, lane = tid & 63, w = tid >> 6;
  const long b = blockIdx.x;
  const float* srow = scores + b;        // stride 512 per t
  float s0[4];
  #pragma unroll
  for (int i = 0; i < 4; ++i) {
    int t = tid + i * 256;
    s0[i] = (t < TS) ? srow[(long)t * 512] : -1e30f;
  }
  float mx = fmaxf(fmaxf(s0[0], s0[1]), fmaxf(s0[2], s0[3]));
  #pragma unroll
  for (int off = 32; off > 0; off >>= 1) mx = fmaxf(mx, __shfl_xor(mx, off, 64));
  if (lane == 0) red[w] = mx;
  __syncthreads();
  mx = fmaxf(fmaxf(red[0], red[1]), fmaxf(red[2], red[3]));
  float sum = 0.f;
  #pragma unroll
  for (int i = 0; i < 4; ++i) {
    int t = tid + i * 256;
    if (t < TS) { float e = __expf(s0[i] - mx); sc[t] = e; sum += e; }
  }
  #pragma unroll
  for (int off = 32; off > 0; off >>= 1) sum += __shfl_xor(sum, off, 64);
  if (lane == 0) red[4 + w] = sum;
  __syncthreads();
  float inv = 1.f / (red[4] + red[5] + red[6] + red[7]);
  const int jg = tid & 31, sl = tid >> 5;
  float acc[4] = {0.f, 0.f, 0.f, 0.f};
  const u16* gbase = gout + b * NH + jg * 4;   // stride 512*NH per t
  for (int t = sl; t < TS; t += 8) {
    float wt = sc[t];
    ushort4 g4 = *(const ushort4*)(gbase + (long)t * (512 * NH));
    acc[0] = fmaf(wt, bf2f(g4.x), acc[0]);
    acc[1] = fmaf(wt, bf2f(g4.y), acc[1]);
    acc[2] = fmaf(wt, bf2f(g4.z), acc[2]);
    acc[3] = fmaf(wt, bf2f(g4.w), acc[3]);
  }
  #pragma unroll
  for (int i = 0; i < 4; ++i) part[sl][jg * 4 + i] = acc[i];
  __syncthreads();
  if (tid < 128) {
    float v = 0.f;
    #pragma unroll
    for (int s = 0; s < 8; ++s) v += part[s][tid];
    hann[tid] = v * inv;
  }
  __syncthreads();
  if (tid < 24) {
    float a = headb[tid];
    const float* hwr = headw + tid * 128;
    for (int k = 0; k < 128; k += 4) {
      float4 h4 = *(const float4*)&hann[k];
      float4 w4 = *(const float4*)&hwr[k];
      a = fmaf(h4.x, w4.x, a); a = fmaf(h4.y, w4.y, a);
      a = fmaf(h4.z, w4.z, a); a = fmaf(h4.w, w4.w, a);
    }
    out[b * 24 + tid] = a;
  }
}

extern "C" void kernel_launch(void* const* d_in, const int* in_sizes, int n_in,
                              void* d_out, int out_size, void* d_ws, size_t ws_size,
                              hipStream_t stream) {
  const float* x      = (const float*)d_in[0];
  const float* proj_w = (const float*)d_in[1];
  const float* proj_b = (const float*)d_in[2];
  const float* beta1  = (const float*)d_in[3];
  const float* beta2  = (const float*)d_in[4];
  const float* gwih   = (const float*)d_in[5];
  const float* gwhh   = (const float*)d_in[6];
  const float* gbih   = (const float*)d_in[7];
  const float* gbhh   = (const float*)d_in[8];
  const float* aw1    = (const float*)d_in[9];
  const float* ab1    = (const float*)d_in[10];
  const float* aw2    = (const float*)d_in[11];
  const float* ab2    = (const float*)d_in[12];
  const float* hw     = (const float*)d_in[13];
  const float* hb     = (const float*)d_in[14];
  float* out = (float*)d_out;
  char* ws = (char*)d_ws;

  // Workspace (bytes) — same envelope as R2..R6 (proven to fit):
  u16*   hcomb  = (u16*)(ws);
  u16*   xpbuf  = (u16*)(ws + 201129984L);
  u16*   gru    = (u16*)(ws + 335216640L);
  float* scores = (float*)(ws + 469303296L);
  u16*   wihb   = (u16*)(ws + 471398400L);
  u16*   w1b    = (u16*)(ws + 471545856L);
  float* hstate = (float*)(ws + 471562240L);

  k_prep<<<288, 256, 0, stream>>>(gwih, aw1, wihb, w1b);
  k_front<<<512, 256, 0, stream>>>(x, proj_w, proj_b, beta1, beta2, hcomb);
  for (int c = 0; c < 3; ++c) {
    long rowbase = (long)c * TCH * 512;
    k_xproj<<<dim3(1364, 3), 256, 0, stream>>>(hcomb + rowbase * NC, wihb, gbih, xpbuf);
    // gru(c); for c>=1, 1364 extra blocks run score for chunk c-1 co-resident with gru blocks
    int grid = (c == 0) ? 256 : 256 + 1364;
    long score_base = (long)(c - 1) * TCH * 512;
    k_gru<<<grid, 256, 0, stream>>>(xpbuf, gwhh, gbhh, gru + rowbase * NH, hstate, c == 0 ? 1 : 0,
                                    gru, w1b, ab1, aw2, ab2, scores, score_base);
  }
  k_score<<<1364, 256, 0, stream>>>(gru, w1b, ab1, aw2, ab2, scores, 2L * TCH * 512);
  k_attn<<<512, 256, 0, stream>>>(scores, gru, hw, hb, out);
}

// Round 6
// 964.767 us; speedup vs baseline: 1.5826x; 1.1084x over previous
//
#include <hip/hip_runtime.h>

typedef unsigned short u16;
typedef __attribute__((ext_vector_type(8))) short short8;
typedef __attribute__((ext_vector_type(4))) float f32x4;

__device__ __forceinline__ u16 f2bf(float f) {
  union { float f; unsigned u; } v; v.f = f;
  unsigned r = v.u + 0x7fffu + ((v.u >> 16) & 1u);
  return (u16)(r >> 16);
}
__device__ __forceinline__ u16 truncbf(float f) {
  union { float f; unsigned u; } v; v.f = f;
  return (u16)(v.u >> 16);
}
__device__ __forceinline__ float bf2f(u16 h) {
  union { unsigned u; float f; } v; v.u = ((unsigned)h) << 16;
  return v.f;
}
// async global->LDS, 16B per lane; LDS dest = wave-uniform base (HW adds lane*16), 16B aligned
__device__ __forceinline__ void gll16(const void* g, void* l) {
  __builtin_amdgcn_global_load_lds((const __attribute__((address_space(1))) unsigned*)g,
                                   (__attribute__((address_space(3))) unsigned*)l, 16, 0, 0);
}
// Workgroup barrier that orders LDS only (no vmcnt drain). Used in k_front only (proven win).
__device__ __forceinline__ void bar_lds() {
  asm volatile("s_waitcnt lgkmcnt(0)" ::: "memory");
  __builtin_amdgcn_s_barrier();
  asm volatile("" ::: "memory");
}

// Problem constants
#define BATCH 512
#define TS 1023          // T-1
#define NF 64
#define NS 128
#define NH 128
#define NG 384           // 3H
#define NC 192           // F + SNN
#define CH 128           // R12: t-chunk = 128 (8 chunks: 7x128 + 127); 2 xp slots ping-pong
// All big tensors are t-major: tensor[t][b][feat], flat row m = t*512 + b.

// ---------------- P: weight bf16 conversion ----------------
__global__ void k_prep(const float* __restrict__ wih, const float* __restrict__ w1,
                       u16* __restrict__ wihb, u16* __restrict__ w1b) {
  int i = blockIdx.x * 256 + threadIdx.x;
  if (i < NG * NC) wihb[i] = f2bf(wih[i]);
  if (i < 64 * NH) w1b[i] = f2bf(w1[i]);
}

// ---------------- FRONT: fused delta-GEMM (bf16 hi/lo MFMA) + SNN scan + raw ----------------
// One block per batch b (512 blocks, 256 threads). Streams t in 16 tiles of 64.
__global__ __launch_bounds__(256, 2) void k_front(const float* __restrict__ x,
                                                  const float* __restrict__ pw,
                                                  const float* __restrict__ pb,
                                                  const float* __restrict__ beta1,
                                                  const float* __restrict__ beta2,
                                                  u16* __restrict__ hcomb) {
  __shared__ float hst[64 * 138];                   // 35,328 B (pad 138: quad-writes 2-way free)
  const int tid = threadIdx.x, lane = tid & 63, w = tid >> 6;
  const int m16 = lane & 15, quad = lane >> 4;
  const int b = blockIdx.x;
  const float* xb = x + (long)b * 65536;

  const int tm = (w >> 1) * 32, nn = (w & 1) * 64;

  // B fragments (pw hi/lo) in registers: lane (m16,quad) holds pw[nn+ni*16+m16][kc*32+quad*8 .. +8]
  short8 bh[2][4], bl[2][4];
  #pragma unroll
  for (int kc = 0; kc < 2; ++kc)
    #pragma unroll
    for (int ni = 0; ni < 4; ++ni) {
      const float* src = pw + (nn + ni * 16 + m16) * 64 + kc * 32 + quad * 8;
      f32x4 v0 = *(const f32x4*)src;
      f32x4 v1 = *(const f32x4*)(src + 4);
      #pragma unroll
      for (int jj = 0; jj < 8; ++jj) {
        float v = (jj < 4) ? v0[jj & 3] : v1[jj & 3];
        u16 hh = truncbf(v);
        bh[kc][ni][jj] = (short)hh;
        bl[kc][ni][jj] = (short)f2bf(v - bf2f(hh));
      }
    }

  float b1v = 0.f, b2v = 0.f, m1 = 0.f, s1 = 0.f, m2 = 0.f, s2 = 0.f;
  if (tid < 128) {
    b1v = fminf(fmaxf(beta1[tid], 0.f), 0.99f);
    b2v = fminf(fmaxf(beta2[tid], 0.f), 0.99f);
  }
  float pbv[4];
  #pragma unroll
  for (int ni = 0; ni < 4; ++ni) pbv[ni] = pb[nn + ni * 16 + m16];

  for (int tile = 0; tile < 16; ++tile) {
    const int t0 = tile * 64;
    const int tl = (TS - t0 < 64) ? (TS - t0) : 64;       // 64, last tile 63

    // P3: A fragments direct from global (delta hi/lo on the fly) + MFMA 3-pass
    f32x4 acc[2][4] = {};
    #pragma unroll
    for (int kc = 0; kc < 2; ++kc) {
      short8 ah[2], al[2];
      #pragma unroll
      for (int mi = 0; mi < 2; ++mi) {
        int row = tm + mi * 16 + m16;
        int tA = t0 + row; if (tA > 1022) tA = 1022;      // dead row of last tile, discarded below
        const float* p0 = xb + (long)tA * 64 + kc * 32 + quad * 8;
        f32x4 lo0 = *(const f32x4*)p0;
        f32x4 lo1 = *(const f32x4*)(p0 + 4);
        f32x4 hi0 = *(const f32x4*)(p0 + 64);
        f32x4 hi1 = *(const f32x4*)(p0 + 68);
        float d[8];
        #pragma unroll
        for (int jj = 0; jj < 4; ++jj) { d[jj] = hi0[jj] - lo0[jj]; d[4 + jj] = hi1[jj] - lo1[jj]; }
        #pragma unroll
        for (int jj = 0; jj < 8; ++jj) {
          u16 hh = truncbf(d[jj]);
          ah[mi][jj] = (short)hh;
          al[mi][jj] = (short)f2bf(d[jj] - bf2f(hh));
        }
      }
      #pragma unroll
      for (int mi = 0; mi < 2; ++mi)
        #pragma unroll
        for (int ni = 0; ni < 4; ++ni) {
          acc[mi][ni] = __builtin_amdgcn_mfma_f32_16x16x32_bf16(ah[mi], bh[kc][ni], acc[mi][ni], 0, 0, 0);
          acc[mi][ni] = __builtin_amdgcn_mfma_f32_16x16x32_bf16(ah[mi], bl[kc][ni], acc[mi][ni], 0, 0, 0);
          acc[mi][ni] = __builtin_amdgcn_mfma_f32_16x16x32_bf16(al[mi], bh[kc][ni], acc[mi][ni], 0, 0, 0);
        }
    }
    // P4: hst[t][n] = acc + proj_b (C/D layout: col=lane&15, row=quad*4+reg)
    #pragma unroll
    for (int mi = 0; mi < 2; ++mi)
      #pragma unroll
      for (int ni = 0; ni < 4; ++ni)
        #pragma unroll
        for (int rr = 0; rr < 4; ++rr)
          hst[(tm + mi * 16 + quad * 4 + rr) * 138 + nn + ni * 16 + m16] = acc[mi][ni][rr] + pbv[ni];
    bar_lds();
    // P5: SNN scan (threads 0..127) + raw emit (threads 128..255, reads global directly)
    if (tid < 128) {
      const int n = tid;
      u16* dst = hcomb + ((long)t0 * 512 + b) * NC + 64 + n;
      for (int tt = 0; tt < tl; tt += 8) {
        float v[8];
        #pragma unroll
        for (int jj = 0; jj < 8; ++jj) {
          int t = tt + jj; if (t > 63) t = 63;
          v[jj] = hst[t * 138 + n];
        }
        #pragma unroll
        for (int jj = 0; jj < 8; ++jj) {
          int t = tt + jj;
          if (t < tl) {
            m1 = b1v * m1 + v[jj] - s1;
            s1 = (m1 > 1.0f) ? 1.0f : 0.0f;
            m2 = b2v * m2 + s1 - s2;
            s2 = (m2 > 1.0f) ? 1.0f : 0.0f;
            dst[(long)t * (512 * NC)] = f2bf(m2);
          }
        }
      }
    } else {
      const int f = tid & 63, half = (tid >> 6) & 1;
      for (int r = half; r < tl; r += 2)
        hcomb[((long)(t0 + r) * 512 + b) * NC + f] = f2bf(xb[(long)(t0 + r + 1) * 64 + f]);
    }
    bar_lds();
  }
}

// ---------------- xproj body: 128x128 tile of h_comb @ W_ih^T + b_ih ----------------
// row0 is chunk-LOCAL row; hc/xp are chunk-base pointers. BK=32, 6 k-chunks.
__device__ __forceinline__ void xproj_body(long row0, int n0, const u16* __restrict__ hc,
                                           const u16* __restrict__ wih, const float* __restrict__ bih,
                                           u16* __restrict__ xp, u16* As, u16* Bs) {
  const int tid = threadIdx.x, lane = tid & 63, w = tid >> 6;
  const int m16 = lane & 15, quad = lane >> 4;
  const int wm = (w >> 1) * 64, wn = (w & 1) * 64;
  f32x4 acc[4][4] = {};
  const char* gA = (const char*)hc + (row0 + (lane >> 2)) * (NC * 2) + (lane & 3) * 16;
  const char* gB = (const char*)wih + (long)(n0 + (lane >> 2)) * (NC * 2) + (lane & 3) * 16;
  for (int kc = 0; kc < 6; ++kc) {
    #pragma unroll
    for (int i = 0; i < 2; ++i) {
      int q = i * 4 + w;
      gll16(gA + (long)q * 16 * (NC * 2) + kc * 64, (char*)As + q * 1024);
      gll16(gB + (long)q * 16 * (NC * 2) + kc * 64, (char*)Bs + q * 1024);
    }
    __syncthreads();
    short8 af[4], bfr[4];
    #pragma unroll
    for (int mi = 0; mi < 4; ++mi) af[mi] = *(const short8*)((const char*)As + (wm + mi * 16 + m16) * 64 + quad * 16);
    #pragma unroll
    for (int ni = 0; ni < 4; ++ni) bfr[ni] = *(const short8*)((const char*)Bs + (wn + ni * 16 + m16) * 64 + quad * 16);
    #pragma unroll
    for (int mi = 0; mi < 4; ++mi)
      #pragma unroll
      for (int ni = 0; ni < 4; ++ni)
        acc[mi][ni] = __builtin_amdgcn_mfma_f32_16x16x32_bf16(af[mi], bfr[ni], acc[mi][ni], 0, 0, 0);
    __syncthreads();
  }
  #pragma unroll
  for (int ni = 0; ni < 4; ++ni) {
    int n = n0 + wn + ni * 16 + m16;
    float bias = bih[n];
    #pragma unroll
    for (int mi = 0; mi < 4; ++mi) {
      long r = row0 + wm + mi * 16 + quad * 4;
      #pragma unroll
      for (int rr = 0; rr < 4; ++rr)
        xp[(r + rr) * NG + n] = f2bf(acc[mi][ni][rr] + bias);
    }
  }
}

// ---------------- C: standalone xproj (chunk 0 prologue), grid (rows/128, 3) ----------------
__global__ __launch_bounds__(256) void k_xproj(const u16* __restrict__ hc, const u16* __restrict__ wih,
                                               const float* __restrict__ bih, u16* __restrict__ xp) {
  __shared__ alignas(16) u16 As[4096], Bs[4096];
  xproj_body((long)blockIdx.x * 128, blockIdx.y * 128, hc, wih, bih, xp, As, Bs);
}

// ---------------- score body: scores = relu(g@W1^T + b1)@w2 + b2 for one 128-row block ----------------
__device__ __forceinline__ void score_body(long row0, const u16* __restrict__ gbf, const u16* __restrict__ w1,
                                           const float* __restrict__ b1, const float* __restrict__ w2,
                                           const float* __restrict__ b2, float* __restrict__ scores,
                                           u16* Gs, u16* Ws) {
  const int tid = threadIdx.x, lane = tid & 63, w = tid >> 6;
  const int m16 = lane & 15, quad = lane >> 4;
  f32x4 acc[2][4] = {};
  const char* gG = (const char*)gbf + (row0 + (lane >> 2)) * (NH * 2) + (lane & 3) * 16;
  const char* gW = (const char*)w1 + (long)(w * 16 + (lane >> 2)) * (NH * 2) + (lane & 3) * 16;
  for (int kc = 0; kc < 4; ++kc) {
    #pragma unroll
    for (int i = 0; i < 2; ++i) {
      int q = i * 4 + w;
      gll16(gG + (long)q * 16 * (NH * 2) + kc * 64, (char*)Gs + q * 1024);
    }
    gll16(gW + kc * 64, (char*)Ws + w * 1024);
    __syncthreads();
    short8 af[2], bfr[4];
    #pragma unroll
    for (int mi = 0; mi < 2; ++mi) af[mi] = *(const short8*)((const char*)Gs + (w * 32 + mi * 16 + m16) * 64 + quad * 16);
    #pragma unroll
    for (int ni = 0; ni < 4; ++ni) bfr[ni] = *(const short8*)((const char*)Ws + (ni * 16 + m16) * 64 + quad * 16);
    #pragma unroll
    for (int mi = 0; mi < 2; ++mi)
      #pragma unroll
      for (int ni = 0; ni < 4; ++ni)
        acc[mi][ni] = __builtin_amdgcn_mfma_f32_16x16x32_bf16(af[mi], bfr[ni], acc[mi][ni], 0, 0, 0);
    __syncthreads();
  }
  float b2v = b2[0];
  float w2v[4], b1v[4];
  #pragma unroll
  for (int ni = 0; ni < 4; ++ni) { w2v[ni] = w2[ni * 16 + m16]; b1v[ni] = b1[ni * 16 + m16]; }
  #pragma unroll
  for (int mi = 0; mi < 2; ++mi) {
    #pragma unroll
    for (int rr = 0; rr < 4; ++rr) {
      float v = 0.f;
      #pragma unroll
      for (int ni = 0; ni < 4; ++ni) {
        float hv = acc[mi][ni][rr] + b1v[ni];
        hv = hv > 0.f ? hv : 0.f;
        v = fmaf(hv, w2v[ni], v);
      }
      v += __shfl_xor(v, 1, 64); v += __shfl_xor(v, 2, 64);
      v += __shfl_xor(v, 4, 64); v += __shfl_xor(v, 8, 64);
      if (m16 == 0) scores[row0 + w * 32 + mi * 16 + quad * 4 + rr] = v + b2v;
    }
  }
}

// ---------------- E: standalone score kernel (last chunk tail) ----------------
__global__ __launch_bounds__(256) void k_score(const u16* __restrict__ gbf, const u16* __restrict__ w1,
                                               const float* __restrict__ b1, const float* __restrict__ w2,
                                               const float* __restrict__ b2, float* __restrict__ scores,
                                               long row_base) {
  __shared__ alignas(16) u16 Gs[4096], Ws[2048];
  score_body(row_base + (long)blockIdx.x * 128, gbf, w1, b1, w2, b2, scores, Gs, Ws);
}

// ---------------- D: pipelined GRU dispatch ----------------
// Blocks 0..255: GRU chunk c (proven R7 step, parameterized nsteps). Blocks 256..256+nxp:
// xproj for chunk c+1 into the OTHER xp slot (disjoint from the slot gru reads — ping-pong).
// Blocks 256+nxp..: score for chunk c-1 (gout rows finished last dispatch). With
// __launch_bounds__(256,2) (R11-verified): 1 gru + 1 shadow block co-resident per CU; shadow
// work runs in gru's ~65% idle issue slots (R11 measured +2us interference for score blocks).
__global__ __launch_bounds__(256, 2) void k_gru(const u16* __restrict__ xp, const float* __restrict__ whh,
                                                const float* __restrict__ bhh, u16* __restrict__ gout,
                                                float* __restrict__ h_state, int first, int nsteps,
                                                const u16* __restrict__ hcN, const u16* __restrict__ wihb,
                                                const float* __restrict__ bih, u16* __restrict__ xpN,
                                                int nxr, int nxp,
                                                const u16* __restrict__ gbf, const u16* __restrict__ w1,
                                                const float* __restrict__ b1, const float* __restrict__ w2,
                                                const float* __restrict__ b2, float* __restrict__ scores,
                                                long score_base) {
  __shared__ alignas(16) u16 frag[2 * 2048];   // gru: two 4KB A-fragment ping-pong buffers
  __shared__ alignas(16) u16 smem[8192];       // shadow paths: xproj As|Bs / score Gs|Ws (16KB)
  if (blockIdx.x >= 256) {
    int ebid = blockIdx.x - 256;
    if (ebid < nxp)
      xproj_body((long)(ebid % nxr) * 128, (ebid / nxr) * 128, hcN, wihb, bih, xpN, smem, smem + 4096);
    else
      score_body(score_base + (long)(ebid - nxp) * 128, gbf, w1, b1, w2, b2, scores, smem, smem + 4096);
    return;
  }
  const int tid = threadIdx.x, lane = tid & 63, w = tid >> 6;
  const int m16 = lane & 15, quad = lane >> 4;
  const long bg0 = (long)blockIdx.x * 2;
  // zero both buffers (invalid A rows harmless for D rows we read, but keep deterministic)
  {
    short8 z8 = {};
    *(short8*)((char*)frag + tid * 16) = z8;
    *(short8*)((char*)frag + 4096 + tid * 16) = z8;
  }
  // W_hh fragments: tile nt = g*2+hh -> B rows g*128 + 32w + hh*16 + m16, k = c*32 + quad*8 + i
  short8 wf[6][4];
  #pragma unroll
  for (int g = 0; g < 3; ++g)
    #pragma unroll
    for (int hh = 0; hh < 2; ++hh)
      #pragma unroll
      for (int c = 0; c < 4; ++c) {
        const float* src = whh + (long)(g * 128 + 32 * w + hh * 16 + m16) * NH + c * 32 + quad * 8;
        short8 v;
        #pragma unroll
        for (int jj = 0; jj < 8; ++jj) v[jj] = (short)f2bf(src[jj]);
        wf[g * 2 + hh][c] = v;
      }
  const int bq = quad & 1, hq = quad >> 1;
  const int j = 32 * w + hq * 16 + m16;        // this lane's j (all 64 lanes distinct (bq,j))
  const long brow = bg0 + bq;
  const float br_ = bhh[j], bz_ = bhh[128 + j], bn_ = bhh[256 + j];
  float h = first ? 0.f : h_state[brow * NH + j];
  // frag byte addr for A[m=4*bq][k=j] (c = j>>5 = w): second copy at m+8 -> +128 bytes
  const int fragoff = w * 1024 + 64 * bq + 256 * (hq * 2 + (m16 >> 3)) + 2 * (m16 & 7);
  __syncthreads();                             // zero-init visible
  {
    u16 hb0 = f2bf(h);
    *(u16*)((char*)frag + fragoff) = hb0;
    *(u16*)((char*)frag + fragoff + 128) = hb0;
  }
  const u16* xbase = xp + brow * NG + j;       // + t*512*NG; gates at +0,+128,+256
  u16 pr[8], pz[8], pn[8], sbuf[8];
  #pragma unroll
  for (int u = 0; u < 8; ++u) {
    const u16* xr = xbase + (long)u * (512 * NG);
    pr[u] = xr[0]; pz[u] = xr[128]; pn[u] = xr[256];
  }
  __syncthreads();

#define GRU_STEP(T, U)                                                                     \
  {                                                                                        \
    const int cur = ((T) & 1) * 4096, nxt = 4096 - cur;                                    \
    short8 af[4];                                                                          \
    _Pragma("unroll")                                                                      \
    for (int c = 0; c < 4; ++c)                                                            \
      af[c] = *(const short8*)((const char*)frag + cur + c * 1024 + lane * 16);            \
    f32x4 zero = {0.f, 0.f, 0.f, 0.f};                                                     \
    f32x4 accA[6], accB[6];                                                                \
    _Pragma("unroll")                                                                      \
    for (int nt = 0; nt < 6; ++nt) {                                                       \
      accA[nt] = __builtin_amdgcn_mfma_f32_16x16x32_bf16(af[0], wf[nt][0], zero, 0, 0, 0); \
      accB[nt] = __builtin_amdgcn_mfma_f32_16x16x32_bf16(af[2], wf[nt][2], zero, 0, 0, 0); \
    }                                                                                      \
    _Pragma("unroll")                                                                      \
    for (int nt = 0; nt < 6; ++nt) {                                                       \
      accA[nt] = __builtin_amdgcn_mfma_f32_16x16x32_bf16(af[1], wf[nt][1], accA[nt], 0, 0, 0); \
      accB[nt] = __builtin_amdgcn_mfma_f32_16x16x32_bf16(af[3], wf[nt][3], accB[nt], 0, 0, 0); \
    }                                                                                      \
    float ghr = (hq ? (accA[1][0] + accB[1][0]) : (accA[0][0] + accB[0][0])) + br_;        \
    float ghz = (hq ? (accA[3][0] + accB[3][0]) : (accA[2][0] + accB[2][0])) + bz_;        \
    float ghn = (hq ? (accA[5][0] + accB[5][0]) : (accA[4][0] + accB[4][0])) + bn_;        \
    float xrv = bf2f(pr[U]), xzv = bf2f(pz[U]), xnv = bf2f(pn[U]);                         \
    float rg = 1.f / (1.f + __expf(-(xrv + ghr)));                                         \
    float zg = 1.f / (1.f + __expf(-(xzv + ghz)));                                         \
    float niv = xnv + rg * ghn;                                                            \
    float ng = 1.f - 2.f / (1.f + __expf(2.f * niv));                                      \
    h = (1.f - zg) * ng + zg * h;                                                          \
    u16 hb = f2bf(h);                                                                      \
    sbuf[U] = hb;                                                                          \
    *(u16*)((char*)frag + nxt + fragoff) = hb;                                             \
    *(u16*)((char*)frag + nxt + fragoff + 128) = hb;                                       \
    __syncthreads();                                                                       \
  }

  const int N8 = nsteps & ~7;                  // full 8-groups (>=120 for nsteps in {127,128})
  for (int t8 = 0; t8 < N8; t8 += 8) {
    // flush previous group's stores (none on first group)
    if (t8 > 0) {
      #pragma unroll
      for (int u = 0; u < 8; ++u)
        gout[((long)(t8 - 8 + u) * 512 + brow) * NH + j] = sbuf[u];
    }
    // prefetch next group's xp (t8+8 .. t8+15, clamped)
    u16 npr[8], npz[8], npn[8];
    #pragma unroll
    for (int u = 0; u < 8; ++u) {
      long tp = t8 + 8 + u; if (tp > nsteps - 1) tp = nsteps - 1;
      const u16* xr = xbase + tp * (512 * NG);
      npr[u] = xr[0]; npz[u] = xr[128]; npn[u] = xr[256];
    }
    GRU_STEP(t8 + 0, 0) GRU_STEP(t8 + 1, 1) GRU_STEP(t8 + 2, 2) GRU_STEP(t8 + 3, 3)
    GRU_STEP(t8 + 4, 4) GRU_STEP(t8 + 5, 5) GRU_STEP(t8 + 6, 6) GRU_STEP(t8 + 7, 7)
    #pragma unroll
    for (int u = 0; u < 8; ++u) { pr[u] = npr[u]; pz[u] = npz[u]; pn[u] = npn[u]; }
  }
  // flush last full group
  #pragma unroll
  for (int u = 0; u < 8; ++u)
    gout[((long)(N8 - 8 + u) * 512 + brow) * NH + j] = sbuf[u];
  // tail steps (0 or 7): pre holds them (clamped prefetch); store immediately.
  // Unrolled + guarded so pr[U]/sbuf[U] indices stay compile-time (no scratch).
  const int tail = nsteps & 7;
  #pragma unroll
  for (int u = 0; u < 7; ++u) {
    if (u < tail) {
      GRU_STEP(N8 + u, u)
      gout[((long)(N8 + u) * 512 + brow) * NH + j] = sbuf[u];
    }
  }
#undef GRU_STEP
  h_state[brow * NH + j] = h;
}

// ---------------- F: softmax over t + weighted sum + head ----------------
// 512 blocks (one per batch) x 256 threads. scores/gout are t-major.
__global__ __launch_bounds__(256) void k_attn(const float* __restrict__ scores, const u16* __restrict__ gout,
                                              const float* __restrict__ headw, const float* __restrict__ headb,
                                              float* __restrict__ out) {
  __shared__ float sc[TS];
  __shared__ float red[8];
  __shared__ float part[8][132];
  __shared__ float hann[128];
  const int tid = threadIdx.x, lane = tid & 63, w = tid >> 6;
  const long b = blockIdx.x;
  const float* srow = scores + b;        // stride 512 per t
  float s0[4];
  #pragma unroll
  for (int i = 0; i < 4; ++i) {
    int t = tid + i * 256;
    s0[i] = (t < TS) ? srow[(long)t * 512] : -1e30f;
  }
  float mx = fmaxf(fmaxf(s0[0], s0[1]), fmaxf(s0[2], s0[3]));
  #pragma unroll
  for (int off = 32; off > 0; off >>= 1) mx = fmaxf(mx, __shfl_xor(mx, off, 64));
  if (lane == 0) red[w] = mx;
  __syncthreads();
  mx = fmaxf(fmaxf(red[0], red[1]), fmaxf(red[2], red[3]));
  float sum = 0.f;
  #pragma unroll
  for (int i = 0; i < 4; ++i) {
    int t = tid + i * 256;
    if (t < TS) { float e = __expf(s0[i] - mx); sc[t] = e; sum += e; }
  }
  #pragma unroll
  for (int off = 32; off > 0; off >>= 1) sum += __shfl_xor(sum, off, 64);
  if (lane == 0) red[4 + w] = sum;
  __syncthreads();
  float inv = 1.f / (red[4] + red[5] + red[6] + red[7]);
  const int jg = tid & 31, sl = tid >> 5;
  float acc[4] = {0.f, 0.f, 0.f, 0.f};
  const u16* gbase = gout + b * NH + jg * 4;   // stride 512*NH per t
  for (int t = sl; t < TS; t += 8) {
    float wt = sc[t];
    ushort4 g4 = *(const ushort4*)(gbase + (long)t * (512 * NH));
    acc[0] = fmaf(wt, bf2f(g4.x), acc[0]);
    acc[1] = fmaf(wt, bf2f(g4.y), acc[1]);
    acc[2] = fmaf(wt, bf2f(g4.z), acc[2]);
    acc[3] = fmaf(wt, bf2f(g4.w), acc[3]);
  }
  #pragma unroll
  for (int i = 0; i < 4; ++i) part[sl][jg * 4 + i] = acc[i];
  __syncthreads();
  if (tid < 128) {
    float v = 0.f;
    #pragma unroll
    for (int s = 0; s < 8; ++s) v += part[s][tid];
    hann[tid] = v * inv;
  }
  __syncthreads();
  if (tid < 24) {
    float a = headb[tid];
    const float* hwr = headw + tid * 128;
    for (int k = 0; k < 128; k += 4) {
      float4 h4 = *(const float4*)&hann[k];
      float4 w4 = *(const float4*)&hwr[k];
      a = fmaf(h4.x, w4.x, a); a = fmaf(h4.y, w4.y, a);
      a = fmaf(h4.z, w4.z, a); a = fmaf(h4.w, w4.w, a);
    }
    out[b * 24 + tid] = a;
  }
}

extern "C" void kernel_launch(void* const* d_in, const int* in_sizes, int n_in,
                              void* d_out, int out_size, void* d_ws, size_t ws_size,
                              hipStream_t stream) {
  const float* x      = (const float*)d_in[0];
  const float* proj_w = (const float*)d_in[1];
  const float* proj_b = (const float*)d_in[2];
  const float* beta1  = (const float*)d_in[3];
  const float* beta2  = (const float*)d_in[4];
  const float* gwih   = (const float*)d_in[5];
  const float* gwhh   = (const float*)d_in[6];
  const float* gbih   = (const float*)d_in[7];
  const float* gbhh   = (const float*)d_in[8];
  const float* aw1    = (const float*)d_in[9];
  const float* ab1    = (const float*)d_in[10];
  const float* aw2    = (const float*)d_in[11];
  const float* ab2    = (const float*)d_in[12];
  const float* hw     = (const float*)d_in[13];
  const float* hb     = (const float*)d_in[14];
  float* out = (float*)d_out;
  char* ws = (char*)d_ws;

  // Workspace (bytes) — same envelope as before (proven to fit). xpbuf region now holds
  // TWO ping-pong slots of 128*512*384 bf16 = 50,331,648 B each (2x = 100.7MB <= 134.1MB).
  u16*   hcomb  = (u16*)(ws);
  u16*   xpbuf  = (u16*)(ws + 201129984L);
  u16*   gru    = (u16*)(ws + 335216640L);
  float* scores = (float*)(ws + 469303296L);
  u16*   wihb   = (u16*)(ws + 471398400L);
  u16*   w1b    = (u16*)(ws + 471545856L);
  float* hstate = (float*)(ws + 471562240L);

  u16* slot[2] = {xpbuf, xpbuf + 25165824L};   // 128*512*384 elems per slot

  k_prep<<<288, 256, 0, stream>>>(gwih, aw1, wihb, w1b);
  k_front<<<512, 256, 0, stream>>>(x, proj_w, proj_b, beta1, beta2, hcomb);
  // prologue: xproj chunk 0 (rows 0..128*512)
  k_xproj<<<dim3(512, 3), 256, 0, stream>>>(hcomb, wihb, gbih, slot[0]);
  // 8-chunk pipeline: dispatch c = gru(c) + xproj(c+1) + score(c-1)
  for (int c = 0; c < 8; ++c) {
    int len = (c == 7) ? 127 : 128;
    long start = (long)c * CH;
    int lenN = (c + 1 == 7) ? 127 : 128;             // next chunk len
    int nxr = (c < 7) ? (lenN * 512 / 128) : 0;      // xproj row-blocks (512 or 508)
    int nxp = nxr * 3;
    int nsc = (c >= 1) ? 512 : 0;                    // prev chunk always len 128 here
    const u16* hcN = hcomb + (start + len) * 512L * NC;
    long score_base = (c >= 1) ? ((long)(c - 1) * CH * 512) : 0;
    k_gru<<<256 + nxp + nsc, 256, 0, stream>>>(
        slot[c & 1], gwhh, gbhh, gru + start * 512L * NH, hstate, c == 0 ? 1 : 0, len,
        hcN, wihb, gbih, slot[(c + 1) & 1], nxr, nxp,
        gru, w1b, ab1, aw2, ab2, scores, score_base);
  }
  // tail: score for chunk 7 (rows 896*512.., 127*512/128 = 508 blocks), then attn
  k_score<<<508, 256, 0, stream>>>(gru, w1b, ab1, aw2, ab2, scores, 896L * 512);
  k_attn<<<512, 256, 0, stream>>>(scores, gru, hw, hb, out);
}